// Round 19
// baseline (176.067 us; speedup 1.0000x reference)
//
#include <hip/hip_runtime.h>
#include <math.h>

typedef float f32x4 __attribute__((ext_vector_type(4)));
typedef __attribute__((ext_vector_type(8))) _Float16 f16x8;
typedef __attribute__((ext_vector_type(4))) _Float16 f16x4;

#define DD 256
#define DH 128
#define NSPLIT 2
#define TROWS 32  // rows per block tile

// ---------------------------------------------------------------------------
// K0 (merged): blocks 0..15: W1 -> f16 MFMA B-fragment order
//   w1f[((kt*8+nt)*64+l)*8+j] = f16(W1[kt*32+(l>>4)*8+j][nt*16+(l&15)])
// blocks 16..: segment boundaries (batch sorted).
// ---------------------------------------------------------------------------
__global__ void ap_setup(const float* __restrict__ W1, _Float16* __restrict__ w1f,
                         const int* __restrict__ batch, int* __restrict__ start,
                         int nrows, int bseg) {
  const int bid = blockIdx.x;
  if (bid < 16) {
    int t = bid * 256 + threadIdx.x;  // 0..4095
    int l = t & 63;
    int tile = t >> 6;  // kt*8 + nt
    int kt = tile >> 3, nt = tile & 7;
    int kbase = kt * 32 + (l >> 4) * 8;
    int col = nt * 16 + (l & 15);
#pragma unroll
    for (int j = 0; j < 8; ++j) {
      w1f[t * 8 + j] = (_Float16)W1[(kbase + j) * DH + col];
    }
  } else {
    int i = (bid - 16) * 256 + threadIdx.x;
    if (i >= nrows) return;
    int c = batch[i];
    int p = (i == 0) ? -1 : batch[i - 1];
    for (int b = p + 1; b <= c; ++b) start[b] = i;
    if (i == nrows - 1) {
      for (int b = c + 1; b <= bseg; ++b) start[b] = nrows;
    }
  }
}

// ---------------------------------------------------------------------------
// K2: fused, block = (segment, piece). Round-18 structure (TROWS=32, wave=nt,
// 2 blocks/CU) + 3-buffer 2-tile-deep prefetch: loads for tile n+2 issue at
// iter n; cvt+write of tile n+1 happens EARLY (before MFMA) using data loaded
// a full tile-period (~9000 cyc) ago -> HBM latency fully hidden, no vmcnt
// drain on the critical path. 5-level max reduce (rows span 32 lanes).
// Per-piece online max (shift cancels except the 1e-8 term, ~1e-13 rel).
// Deterministic: fixed-order reductions, no fp atomics.
// ---------------------------------------------------------------------------
__global__ __launch_bounds__(512, 2)
void ap_fused(const float* __restrict__ x, const _Float16* __restrict__ w1f,
              const float* __restrict__ b1, const float* __restrict__ W2,
              const float* __restrict__ b2, const int* __restrict__ start,
              float* __restrict__ pooledPart, float* __restrict__ mPart,
              float* __restrict__ swPart, int nrows) {
  __shared__ __align__(16) _Float16 xsh[2][TROWS * 256];  // 2x16 KB f16 tiles
  __shared__ float praw[2][8][TROWS];                     // 8 nt-partials/row
  __shared__ float swArr[8];

  const int tid = threadIdx.x;
  const int wv = tid >> 6;    // 0..7 ; wave's nt = wv
  const int l = tid & 63;
  const int l15 = l & 15, lhi = l >> 4;

  const int bi = blockIdx.x;
  const int b = bi >> 1;
  const int q = bi & (NSPLIT - 1);
  const int s0 = start[b], e0 = start[b + 1];
  const int cnt = e0 - s0;
  const int L = (cnt + NSPLIT - 1) >> 1;
  const int s = s0 + q * L;
  int pe = s + L;
  if (pe > e0) pe = e0;
  const int e = pe;
  const int ce = (e > 0) ? (e - 1) : 0;  // safe clamp row

  // ---- B fragments -> registers (8 frags = 32 VGPR), from L2 ----
  f16x8 Breg[8];  // [kt], this wave's nt = wv
#pragma unroll
  for (int kt = 0; kt < 8; ++kt) {
    Breg[kt] = *((const f16x8*)w1f + (size_t)(kt * 8 + wv) * 64 + l);
  }
  const float b1f = b1[wv * 16 + l15];
  const float w2f = W2[wv * 16 + l15];
  const float bb = *b2;
  const float NI = -__builtin_inff();

  f32x4 accp = {0.f, 0.f, 0.f, 0.f};  // lane-local pooled chunk (cols l*4..)
  float m = NI;
  float swv = 0.f;

  // clamped coalesced row load: lane l = chunk l of row (base + wv*4 + i)
#define LOAD4(dst, base)                                        \
  {                                                             \
    _Pragma("unroll") for (int i = 0; i < 4; ++i) {             \
      int grow = (base) + wv * 4 + i;                           \
      if (grow > ce) grow = ce;                                 \
      if (grow < 0) grow = 0;                                   \
      dst[i] = *(const f32x4*)(x + (size_t)grow * DD + l * 4);  \
    }                                                           \
  }
#define CVTWRITE(src, bufidx)                                   \
  {                                                             \
    _Pragma("unroll") for (int i = 0; i < 4; ++i) {             \
      const int R = wv * 4 + i;                                 \
      const int gp = l ^ ((R & 7) << 1);                        \
      f16x4 h4;                                                 \
      _Pragma("unroll") for (int j = 0; j < 4; ++j)             \
          h4[j] = (_Float16)src[i][j];                          \
      *(f16x4*)(xsh[bufidx] + (size_t)(R * 64 + gp) * 4) = h4;  \
    }                                                           \
  }

  // prologue: xc0 = tile0 (cvt+write xs[0]); xc1 = tile1 (clamped)
  f32x4 xc0[4], xc1[4], xc2[4];
  LOAD4(xc0, s);
  CVTWRITE(xc0, 0);
  LOAD4(xc1, s + TROWS);
  __syncthreads();  // xs[0] ready

  int buf = 0;
  for (int t0 = s; t0 < e; t0 += TROWS) {
    const bool hasNext = (t0 + TROWS < e);

    // ---- (1) issue loads for tile n+2 (consumed next iteration) ----
    LOAD4(xc2, t0 + 2 * TROWS);

    // ---- (2) EARLY cvt+write tile n+1 into xs[buf^1] (data ~1 tile old;
    //          ds_writes drain under the MFMA phase below) ----
    if (hasNext) CVTWRITE(xc1, buf ^ 1);

    // ---- (3) MFMA: A from xs[buf] (2 row-groups), B from registers ----
    f32x4 acc[2];
#pragma unroll
    for (int rg2 = 0; rg2 < 2; ++rg2) acc[rg2] = f32x4{0.f, 0.f, 0.f, 0.f};
#pragma unroll
    for (int kt = 0; kt < 8; ++kt) {
#pragma unroll
      for (int rg2 = 0; rg2 < 2; ++rg2) {
        const int Rr = rg2 * 16 + l15;
        const int gp = (kt * 8 + lhi * 2) ^ ((Rr & 7) << 1);
        const f16x8 ah = *(const f16x8*)(xsh[buf] + (size_t)(Rr * 64 + gp) * 4);
        acc[rg2] =
            __builtin_amdgcn_mfma_f32_16x16x32_f16(ah, Breg[kt], acc[rg2], 0, 0, 0);
      }
    }

    // ---- (4) epilogue: relu+b1, dot W2 (wave's 16 cols), reduce l15 ----
    float pr[2][4];
#pragma unroll
    for (int rg2 = 0; rg2 < 2; ++rg2)
#pragma unroll
      for (int r = 0; r < 4; ++r)
        pr[rg2][r] = fmaxf(acc[rg2][r] + b1f, 0.f) * w2f;
#pragma unroll
    for (int mm = 1; mm < 16; mm <<= 1) {
#pragma unroll
      for (int rg2 = 0; rg2 < 2; ++rg2)
#pragma unroll
        for (int r = 0; r < 4; ++r) pr[rg2][r] += __shfl_xor(pr[rg2][r], mm, 64);
    }
    if (l15 == 0) {
#pragma unroll
      for (int rg2 = 0; rg2 < 2; ++rg2)
#pragma unroll
        for (int r = 0; r < 4; ++r)
          praw[buf][wv][rg2 * 16 + lhi * 4 + r] = pr[rg2][r];
    }

    __syncthreads();  // (5) the ONE barrier per tile

    // ---- (6) block-uniform online softmax over the 32 tile rows ----
    const int lr = l & 31;  // lanes 32..63 duplicate rows 0..31
    float tot = NI;
    if (t0 + lr < e) {
      tot = bb;
#pragma unroll
      for (int p = 0; p < 8; ++p) tot += praw[buf][p][lr];
    }
    float tv = tot;
#pragma unroll
    for (int mm = 1; mm < 32; mm <<= 1) tv = fmaxf(tv, __shfl_xor(tv, mm, 64));
    const float nm = fmaxf(m, tv);       // row t0 valid -> finite
    const float factor = expf(m - nm);   // first tile: exp(-inf) = 0
    m = nm;
    accp *= factor;
    swv *= factor;

    // ---- (7) pooling from the LIVE xc0 fp32 registers (4 rows/wave) ----
#pragma unroll
    for (int i = 0; i < 4; ++i) {
      const int R = wv * 4 + i;
      const float wi = expf(__shfl(tot, R, 64) - m);  // invalid row -> 0
      swv += wi;
      accp += wi * xc0[i];
    }
    // rotate prefetch buffers
#pragma unroll
    for (int i = 0; i < 4; ++i) { xc0[i] = xc1[i]; xc1[i] = xc2[i]; }
    buf ^= 1;
  }
#undef LOAD4
#undef CVTWRITE

  // ---- combine 8 wave partials (m is block-uniform), write piece ----
  __syncthreads();                       // xs free; alias xsh as pooled
  float* pooled = (float*)xsh;           // 8x256 f32 = 8 KB (fits 32 KB)
  *(f32x4*)(pooled + (size_t)(wv * 256 + l * 4)) = accp;
  if (l == 0) swArr[wv] = swv;
  __syncthreads();
  if (tid < 64) {
    float sum_w = 0.f;
#pragma unroll
    for (int p = 0; p < 8; ++p) sum_w += swArr[p];
    const f32x4* pw = (const f32x4*)pooled;
    f32x4 v = ((pw[0 * 64 + tid] + pw[1 * 64 + tid]) +
               (pw[2 * 64 + tid] + pw[3 * 64 + tid]));
    f32x4 w = ((pw[4 * 64 + tid] + pw[5 * 64 + tid]) +
               (pw[6 * 64 + tid] + pw[7 * 64 + tid]));
    *(f32x4*)(pooledPart + (size_t)bi * DD + tid * 4) = v + w;
    if (tid == 0) { mPart[bi] = m; swPart[bi] = sum_w; }
  }
}

// ---------------------------------------------------------------------------
// K3: merge the NSPLIT piece partials per segment (fixed order), scale, write.
// ---------------------------------------------------------------------------
__global__ __launch_bounds__(64)
void ap_final(const float* __restrict__ pooledPart, const float* __restrict__ mPart,
              const float* __restrict__ swPart, const int* __restrict__ start,
              float* __restrict__ out, int nrows) {
  const int b = blockIdx.x;
  const int tid = threadIdx.x;
  const float NI = -__builtin_inff();
  float mq[NSPLIT];
#pragma unroll
  for (int qv = 0; qv < NSPLIT; ++qv) mq[qv] = mPart[b * NSPLIT + qv];
  float m_f = NI;
#pragma unroll
  for (int qv = 0; qv < NSPLIT; ++qv) m_f = fmaxf(m_f, mq[qv]);
  float fac[NSPLIT];
  float sum_w = 0.f;
#pragma unroll
  for (int qv = 0; qv < NSPLIT; ++qv) {
    fac[qv] = (mq[qv] == NI) ? 0.f : expf(mq[qv] - m_f);
    sum_w += swPart[b * NSPLIT + qv] * fac[qv];
  }
  const int cnt = start[b + 1] - start[b];
  const float cntf = (float)(cnt > 0 ? cnt : 1);
  const float scale = 1.0f / (((sum_w / cntf) * (float)nrows + 1e-8f) * cntf);
  f32x4 r = f32x4{0.f, 0.f, 0.f, 0.f};
#pragma unroll
  for (int qv = 0; qv < NSPLIT; ++qv) {
    r += ((const f32x4*)(pooledPart + (size_t)(b * NSPLIT + qv) * DD))[tid] * fac[qv];
  }
  r *= scale;
  *(f32x4*)(out + (size_t)b * DD + tid * 4) = r;
}

extern "C" void kernel_launch(void* const* d_in, const int* in_sizes, int n_in,
                              void* d_out, int out_size, void* d_ws, size_t ws_size,
                              hipStream_t stream) {
  const float* x     = (const float*)d_in[0];
  const int*   batch = (const int*)d_in[1];
  const float* W1    = (const float*)d_in[2];
  const float* b1    = (const float*)d_in[3];
  const float* W2    = (const float*)d_in[4];
  const float* b2    = (const float*)d_in[5];
  float* out = (float*)d_out;

  const int nrows = in_sizes[1];
  const int bseg = out_size / DD;

  // workspace layout (16B-aligned)
  float* pooledPart = (float*)d_ws;                        // bseg*2*256 f32
  float* mPart  = pooledPart + (size_t)bseg * NSPLIT * DD; // bseg*2
  float* swPart = mPart + bseg * NSPLIT;                   // bseg*2
  _Float16* w1f = (_Float16*)(swPart + bseg * NSPLIT);     // 64 KB
  int* start = (int*)(w1f + 64 * 64 * 8);                  // bseg+1

  ap_setup<<<16 + (nrows + 255) / 256, 256, 0, stream>>>(W1, w1f, batch, start,
                                                         nrows, bseg);
  ap_fused<<<bseg * NSPLIT, 512, 0, stream>>>(x, w1f, b1, W2, b2, start,
                                              pooledPart, mPart, swPart, nrows);
  ap_final<<<bseg, 64, 0, stream>>>(pooledPart, mPart, swPart, start, out, nrows);
}

// Round 20
// 130.224 us; speedup vs baseline: 1.3520x; 1.3520x over previous
//
#include <hip/hip_runtime.h>
#include <math.h>

typedef float f32x4 __attribute__((ext_vector_type(4)));
typedef __attribute__((ext_vector_type(8))) _Float16 f16x8;
typedef __attribute__((ext_vector_type(4))) _Float16 f16x4;

#define DD 256
#define DH 128
#define TROWS 64  // rows per block tile

// ---------------------------------------------------------------------------
// K0 (merged): blocks 0..15: W1 -> f16 MFMA B-fragment order
//   w1f[((kt*8+nt)*64+l)*8+j] = f16(W1[kt*32+(l>>4)*8+j][nt*16+(l&15)])
// blocks 16..: segment boundaries (batch sorted).
// ---------------------------------------------------------------------------
__global__ void ap_setup(const float* __restrict__ W1, _Float16* __restrict__ w1f,
                         const int* __restrict__ batch, int* __restrict__ start,
                         int nrows, int bseg) {
  const int bid = blockIdx.x;
  if (bid < 16) {
    int t = bid * 256 + threadIdx.x;  // 0..4095
    int l = t & 63;
    int tile = t >> 6;  // kt*8 + nt
    int kt = tile >> 3, nt = tile & 7;
    int kbase = kt * 32 + (l >> 4) * 8;
    int col = nt * 16 + (l & 15);
#pragma unroll
    for (int j = 0; j < 8; ++j) {
      w1f[t * 8 + j] = (_Float16)W1[(kbase + j) * DH + col];
    }
  } else {
    int i = (bid - 16) * 256 + threadIdx.x;
    if (i >= nrows) return;
    int c = batch[i];
    int p = (i == 0) ? -1 : batch[i - 1];
    for (int b = p + 1; b <= c; ++b) start[b] = i;
    if (i == nrows - 1) {
      for (int b = c + 1; b <= bseg; ++b) start[b] = nrows;
    }
  }
}

// ---------------------------------------------------------------------------
// K2: fused, ONE block per segment, direct output write (no merge kernel,
// no partials round-trip). Round-16 pipeline verbatim: f16-only MLP (the
// absmax floor is reduction-order, not MLP precision), double-buffered x
// tile, ONE barrier per tile:
//   [prefetch || MFMA(xs[cur]) || epilogue->praw[cur] || cvt+write xs[nxt]]
//   -> barrier -> [softmax+pool from praw[cur] + xcol regs]
// Coalesced x loads (lane=chunk, 1KB/instr); B in LDS (64 KB, staged once).
// Per-segment online max (shift cancels except the 1e-8 term, ~1e-13 rel).
// Empty segment: sum_w=0 -> out=0 (matches reference). Deterministic:
// fixed-order reductions, no fp atomics.
// ---------------------------------------------------------------------------
__global__ __launch_bounds__(512)
void ap_fused(const float* __restrict__ x, const _Float16* __restrict__ w1f,
              const float* __restrict__ b1, const float* __restrict__ W2,
              const float* __restrict__ b2, const int* __restrict__ start,
              float* __restrict__ out, int nrows) {
  __shared__ __align__(16) _Float16 xsh[2][TROWS * 256];  // 2x32 KB f16 tiles
  __shared__ __align__(16) _Float16 sB[64 * 64 * 8];      // 64 KB B fragments
  __shared__ float praw[2][2][TROWS];
  __shared__ float swArr[8];

  const int tid = threadIdx.x;
  const int wv = tid >> 6;   // 0..7
  const int g = wv >> 1;     // 16-row group 0..3
  const int hw = wv & 1;     // half: nt hw*4..
  const int l = tid & 63;
  const int l15 = l & 15, lhi = l >> 4;

  const int b = blockIdx.x;
  const int s = start[b], e = start[b + 1];
  const int ce = (e > 0) ? (e - 1) : 0;  // safe clamp row

  // stage B fragments into LDS (once per block)
  {
    const f32x4* src = (const f32x4*)w1f;
    f32x4* dst = (f32x4*)sB;
#pragma unroll
    for (int it = 0; it < 8; ++it) dst[it * 512 + tid] = src[it * 512 + tid];
  }

  float b1f[4], w2f[4];
#pragma unroll
  for (int nt = 0; nt < 4; ++nt) {
    const int idx = (hw * 4 + nt) * 16 + l15;
    b1f[nt] = b1[idx];
    w2f[nt] = W2[idx];
  }
  const float bb = *b2;
  const float NI = -__builtin_inff();

  f32x4 accp = {0.f, 0.f, 0.f, 0.f};  // lane-local pooled chunk (cols l*4..)
  float m = NI;
  float swv = 0.f;

  // prologue: load tile0 rows (coalesced), convert+write xs[0]
  f32x4 xcol[8], xnext[8];
#pragma unroll
  for (int i = 0; i < 8; ++i) {
    const int R = g * 16 + hw * 8 + i;
    int grow = s + R;
    if (grow > ce) grow = ce;
    if (grow < 0) grow = 0;
    xcol[i] = *(const f32x4*)(x + (size_t)grow * DD + l * 4);
  }
#pragma unroll
  for (int i = 0; i < 8; ++i) {
    const int R = g * 16 + hw * 8 + i;
    const int gp = l ^ ((R & 7) << 1);
    f16x4 h4;
#pragma unroll
    for (int j = 0; j < 4; ++j) h4[j] = (_Float16)xcol[i][j];
    *(f16x4*)(xsh[0] + (size_t)(R * 64 + gp) * 4) = h4;
  }
  __syncthreads();  // sB + xs[0] ready

  int buf = 0;
  for (int t0 = s; t0 < e; t0 += TROWS) {
    const bool hasNext = (t0 + TROWS < e);

    // ---- (1) prefetch next tile rows ----
    if (hasNext) {
#pragma unroll
      for (int i = 0; i < 8; ++i) {
        const int R = g * 16 + hw * 8 + i;
        int grow = t0 + TROWS + R;
        if (grow > ce) grow = ce;
        xnext[i] = *(const f32x4*)(x + (size_t)grow * DD + l * 4);
      }
    }

    // ---- (2) MFMA: A = f16x8 reads from xs[buf], B from LDS ----
    f32x4 acc[4];
#pragma unroll
    for (int nt = 0; nt < 4; ++nt) acc[nt] = f32x4{0.f, 0.f, 0.f, 0.f};
    const int Rr = g * 16 + l15;
    const int sxe = (Rr & 7) << 1;
#pragma unroll
    for (int kt = 0; kt < 8; ++kt) {
      const int gp = (kt * 8 + lhi * 2) ^ sxe;  // even: b128-aligned pair
      const f16x8 ah = *(const f16x8*)(xsh[buf] + (size_t)(Rr * 64 + gp) * 4);
#pragma unroll
      for (int nt = 0; nt < 4; ++nt) {
        const f16x8 Bh =
            *((const f16x8*)sB + (size_t)(kt * 8 + hw * 4 + nt) * 64 + l);
        acc[nt] = __builtin_amdgcn_mfma_f32_16x16x32_f16(ah, Bh, acc[nt], 0, 0, 0);
      }
    }

    // ---- (3) epilogue: relu+b1, dot W2, reduce over 16 col-lanes ----
    float pr[4];
#pragma unroll
    for (int r = 0; r < 4; ++r) pr[r] = 0.f;
#pragma unroll
    for (int nt = 0; nt < 4; ++nt) {
#pragma unroll
      for (int r = 0; r < 4; ++r)
        pr[r] += fmaxf(acc[nt][r] + b1f[nt], 0.f) * w2f[nt];
    }
#pragma unroll
    for (int mm = 1; mm < 16; mm <<= 1) {
#pragma unroll
      for (int r = 0; r < 4; ++r) pr[r] += __shfl_xor(pr[r], mm, 64);
    }
    if (l15 == 0) {
#pragma unroll
      for (int r = 0; r < 4; ++r) praw[buf][hw][g * 16 + lhi * 4 + r] = pr[r];
    }

    // ---- (4) convert + write NEXT tile into xs[buf^1] (overlaps MFMA) ----
    if (hasNext) {
#pragma unroll
      for (int i = 0; i < 8; ++i) {
        const int R = g * 16 + hw * 8 + i;
        const int gp = l ^ ((R & 7) << 1);
        f16x4 h4;
#pragma unroll
        for (int j = 0; j < 4; ++j) h4[j] = (_Float16)xnext[i][j];
        *(f16x4*)(xsh[buf ^ 1] + (size_t)(R * 64 + gp) * 4) = h4;
      }
    }

    __syncthreads();  // (5) the ONE barrier per tile

    // ---- (6) block-uniform online softmax over the 64 tile rows ----
    const float tot =
        (t0 + l < e) ? (praw[buf][0][l] + praw[buf][1][l] + bb) : NI;
    float tv = tot;
#pragma unroll
    for (int mm = 1; mm < 64; mm <<= 1) tv = fmaxf(tv, __shfl_xor(tv, mm, 64));
    const float nm = fmaxf(m, tv);       // row t0 valid -> finite
    const float factor = expf(m - nm);   // first tile: exp(-inf) = 0
    m = nm;
    accp *= factor;
    swv *= factor;

    // ---- (7) pooling from the LIVE xcol fp32 registers ----
#pragma unroll
    for (int i = 0; i < 8; ++i) {
      const int R = g * 16 + hw * 8 + i;
      const float wi = expf(__shfl(tot, R, 64) - m);  // invalid row -> 0
      swv += wi;
      accp += wi * xcol[i];
    }
#pragma unroll
    for (int i = 0; i < 8; ++i) xcol[i] = xnext[i];
    buf ^= 1;
  }

  // ---- combine 8 wave partials (m is block-uniform), scale, write out ----
  __syncthreads();                       // xs free; alias xsh as pooled
  float* pooled = (float*)xsh;           // 8x256 f32 = 8 KB
  *(f32x4*)(pooled + (size_t)(wv * 256 + l * 4)) = accp;
  if (l == 0) swArr[wv] = swv;
  __syncthreads();
  if (tid < 64) {
    float sum_w = 0.f;
#pragma unroll
    for (int p = 0; p < 8; ++p) sum_w += swArr[p];
    const f32x4* pw = (const f32x4*)pooled;
    f32x4 v = ((pw[0 * 64 + tid] + pw[1 * 64 + tid]) +
               (pw[2 * 64 + tid] + pw[3 * 64 + tid]));
    f32x4 w = ((pw[4 * 64 + tid] + pw[5 * 64 + tid]) +
               (pw[6 * 64 + tid] + pw[7 * 64 + tid]));
    const int cnt = e - s;
    const float cntf = (float)(cnt > 0 ? cnt : 1);
    const float scale = 1.0f / (((sum_w / cntf) * (float)nrows + 1e-8f) * cntf);
    f32x4 r = (v + w) * scale;
    *(f32x4*)(out + (size_t)b * DD + tid * 4) = r;
  }
}

extern "C" void kernel_launch(void* const* d_in, const int* in_sizes, int n_in,
                              void* d_out, int out_size, void* d_ws, size_t ws_size,
                              hipStream_t stream) {
  const float* x     = (const float*)d_in[0];
  const int*   batch = (const int*)d_in[1];
  const float* W1    = (const float*)d_in[2];
  const float* b1    = (const float*)d_in[3];
  const float* W2    = (const float*)d_in[4];
  const float* b2    = (const float*)d_in[5];
  float* out = (float*)d_out;

  const int nrows = in_sizes[1];
  const int bseg = out_size / DD;

  // workspace layout (16B-aligned)
  _Float16* w1f = (_Float16*)d_ws;                  // 64 KB
  int* start = (int*)(w1f + 64 * 64 * 8);           // bseg+1

  ap_setup<<<16 + (nrows + 255) / 256, 256, 0, stream>>>(W1, w1f, batch, start,
                                                         nrows, bseg);
  ap_fused<<<bseg, 512, 0, stream>>>(x, w1f, b1, W2, b2, start, out, nrows);
}